// Round 7
// baseline (123.938 us; speedup 1.0000x reference)
//
#include <hip/hip_runtime.h>

#define D 64

// ---------- zero deg (replaces 42us hipMemsetAsync fill kernel) ----------
__global__ void k_zero(int* __restrict__ p, int n4) {
    int i = blockIdx.x * blockDim.x + threadIdx.x;
    if (i < n4) *(int4*)&p[i * 4] = make_int4(0, 0, 0, 0);
}

// ---------- in-degree count + per-edge rank: 4 edges/thread ----------
__global__ void k_deg_count(const int* __restrict__ dst, int E, int* deg,
                            int* __restrict__ rank) {
    int i = blockIdx.x * blockDim.x + threadIdx.x;
    int e = i * 4;
    if (e + 4 <= E) {
        int4 d4 = *(const int4*)&dst[e];
        int4 r4;
        r4.x = atomicAdd(&deg[d4.x], 1);
        r4.y = atomicAdd(&deg[d4.y], 1);
        r4.z = atomicAdd(&deg[d4.z], 1);
        r4.w = atomicAdd(&deg[d4.w], 1);
        *(int4*)&rank[e] = r4;   // coalesced
    } else if (e < E) {
        for (; e < E; ++e) rank[e] = atomicAdd(&deg[dst[e]], 1);
    }
}

// ---------- scan phase 1: per-block sums of deg; also dinv = rsqrt(deg+1) ----------
__global__ __launch_bounds__(256) void k_scan_partial(const int* __restrict__ deg,
                                                      int n, int* __restrict__ bsum,
                                                      float* __restrict__ dinv) {
    __shared__ int red[256];
    int t = threadIdx.x;
    int i = blockIdx.x * 256 + t;
    int d = (i < n) ? deg[i] : 0;
    if (i < n) dinv[i] = rsqrtf((float)(d + 1));  // +1 = self-loop
    red[t] = d;
    __syncthreads();
    for (int off = 128; off >= 1; off >>= 1) {
        if (t < off) red[t] += red[t + off];
        __syncthreads();
    }
    if (t == 0) bsum[blockIdx.x] = red[0];
}

// ---------- scan phase 2: one small block scans block sums (nb <= 256) ----------
__global__ __launch_bounds__(256) void k_scan_bsum(int* bsum, int nb) {
    __shared__ int sh[256];
    int t = threadIdx.x;
    sh[t] = (t < nb) ? bsum[t] : 0;
    __syncthreads();
    for (int off = 1; off < 256; off <<= 1) {
        int v = (t >= off) ? sh[t - off] : 0;
        __syncthreads();
        sh[t] += v;
        __syncthreads();
    }
    if (t < nb) bsum[t] = (t == 0) ? 0 : sh[t - 1];
}

// ---------- scan phase 3: row_ptr ----------
__global__ __launch_bounds__(256) void k_scan_final(const int* __restrict__ deg, int n,
                                                    const int* __restrict__ bsum,
                                                    int* row_ptr) {
    __shared__ int sh[256];
    int t = threadIdx.x;
    int i = blockIdx.x * 256 + t;
    int val = (i < n) ? deg[i] : 0;
    sh[t] = val;
    __syncthreads();
    for (int off = 1; off < 256; off <<= 1) {
        int v = (t >= off) ? sh[t - off] : 0;
        __syncthreads();
        sh[t] += v;
        __syncthreads();
    }
    int excl = bsum[blockIdx.x] + sh[t] - val;
    if (i < n) row_ptr[i] = excl;
    if (i == n - 1) row_ptr[n] = excl + val;  // = E
}

// ---------- bucket: NO atomics; pos = row_ptr[dst] + rank; 2 edges/thread ----------
__global__ void k_bucket(const int* __restrict__ src, const int* __restrict__ dst,
                         const int* __restrict__ rank, int E,
                         const int* __restrict__ row_ptr, int* __restrict__ csr_src) {
    int i = blockIdx.x * blockDim.x + threadIdx.x;
    int e = i * 2;
    if (e >= E) return;
    int2 s2 = *(const int2*)&src[e];
    int2 d2 = *(const int2*)&dst[e];
    int2 r2 = *(const int2*)&rank[e];
    csr_src[row_ptr[d2.x] + r2.x] = s2.x;
    if (e + 1 < E) csr_src[row_ptr[d2.y] + r2.y] = s2.y;
}

// ---------- gather: 1 node per wave, 4 edge-slots x 16 dim-groups, unroll x2 ----------
__global__ __launch_bounds__(256) void k_gather(
        const float* __restrict__ x, const float* __restrict__ dinv,
        const int* __restrict__ row_ptr, const int* __restrict__ csr_src,
        float* __restrict__ agg, int n) {
    int tid = threadIdx.x;
    int wave = tid >> 6, lane = tid & 63;
    int eg = lane >> 4, dg = lane & 15;
    int v = blockIdx.x * 4 + wave;
    if (v >= n) return;
    float dv = dinv[v];
    int beg = row_ptr[v], end = row_ptr[v + 1];

    float4 acc = make_float4(0.f, 0.f, 0.f, 0.f);
    if (eg == 0) {  // self-loop term
        float4 xv = *(const float4*)&x[(size_t)v * D + dg * 4];
        float w = dv * dv;
        acc.x = xv.x * w; acc.y = xv.y * w; acc.z = xv.z * w; acc.w = xv.w * w;
    }
    int base = beg;
    for (; base + 8 <= end; base += 8) {  // two independent chains
        int u0 = csr_src[base + eg];
        int u1 = csr_src[base + 4 + eg];
        float n0 = dinv[u0] * dv;
        float n1 = dinv[u1] * dv;
        float4 x0 = *(const float4*)&x[(size_t)u0 * D + dg * 4];
        float4 x1 = *(const float4*)&x[(size_t)u1 * D + dg * 4];
        acc.x = fmaf(x0.x, n0, acc.x); acc.y = fmaf(x0.y, n0, acc.y);
        acc.z = fmaf(x0.z, n0, acc.z); acc.w = fmaf(x0.w, n0, acc.w);
        acc.x = fmaf(x1.x, n1, acc.x); acc.y = fmaf(x1.y, n1, acc.y);
        acc.z = fmaf(x1.z, n1, acc.z); acc.w = fmaf(x1.w, n1, acc.w);
    }
    for (; base < end; base += 4) {
        int idx = base + eg;
        if (idx < end) {
            int u = csr_src[idx];
            float nrm = dinv[u] * dv;
            float4 xv = *(const float4*)&x[(size_t)u * D + dg * 4];
            acc.x = fmaf(xv.x, nrm, acc.x); acc.y = fmaf(xv.y, nrm, acc.y);
            acc.z = fmaf(xv.z, nrm, acc.z); acc.w = fmaf(xv.w, nrm, acc.w);
        }
    }
#pragma unroll
    for (int off = 16; off <= 32; off <<= 1) {
        acc.x += __shfl_xor(acc.x, off, 64);
        acc.y += __shfl_xor(acc.y, off, 64);
        acc.z += __shfl_xor(acc.z, off, 64);
        acc.w += __shfl_xor(acc.w, off, 64);
    }
    if (eg == 0) *(float4*)&agg[(size_t)v * D + dg * 4] = acc;
}

// ---------- dense GEMM + relu + W2-dot: wave per node, 16 nodes/wave ----------
#define NPW 16
__global__ __launch_bounds__(256) void k_gemm(
        const float* __restrict__ agg, const float* __restrict__ dinv,
        const float* __restrict__ W1, const float* __restrict__ b1,
        const float* __restrict__ W2, float* __restrict__ sd, int n) {
    __shared__ float lrow[4][D];
    int tid = threadIdx.x;
    int wave = tid >> 6, lane = tid & 63;
    float w1c[D];
#pragma unroll
    for (int d = 0; d < D; ++d) w1c[d] = W1[d * D + lane];
    float b1l = b1[lane], w2l = W2[lane];
    int v0 = (blockIdx.x * 4 + wave) * NPW;
    for (int k = 0; k < NPW; ++k) {
        int v = v0 + k;
        if (v >= n) break;
        lrow[wave][lane] = agg[(size_t)v * D + lane];  // coalesced 256B
        __builtin_amdgcn_wave_barrier();
        float h = b1l;
#pragma unroll
        for (int db = 0; db < D; db += 4) {
            float4 r = *(const float4*)&lrow[wave][db];  // broadcast ds_read_b128
            h = fmaf(r.x, w1c[db], h);
            h = fmaf(r.y, w1c[db + 1], h);
            h = fmaf(r.z, w1c[db + 2], h);
            h = fmaf(r.w, w1c[db + 3], h);
        }
        float tt = fmaxf(h, 0.0f) * w2l;
#pragma unroll
        for (int off = 1; off <= 32; off <<= 1) tt += __shfl_xor(tt, off, 64);
        if (lane == 0) sd[v] = tt * dinv[v];  // s[v] * dinv[v]
        __builtin_amdgcn_wave_barrier();
    }
}

// ---------- layer-2: 4 lanes per node gather over CSR ----------
__global__ __launch_bounds__(256) void k_out(const float* __restrict__ sd,
        const float* __restrict__ dinv, const int* __restrict__ row_ptr,
        const int* __restrict__ csr_src, const float* __restrict__ b2,
        float* __restrict__ out, int n) {
    int t = blockIdx.x * blockDim.x + threadIdx.x;
    int v = t >> 2, r = t & 3;
    if (v >= n) return;
    int beg = row_ptr[v], end = row_ptr[v + 1];
    float a = (r == 0) ? sd[v] : 0.0f;  // self-loop
    for (int i = beg + r; i < end; i += 4) a += sd[csr_src[i]];
    a += __shfl_xor(a, 1, 64);
    a += __shfl_xor(a, 2, 64);
    if (r == 0) out[v] = b2[0] + a * dinv[v];
}

extern "C" void kernel_launch(void* const* d_in, const int* in_sizes, int n_in,
                              void* d_out, int out_size, void* d_ws, size_t ws_size,
                              hipStream_t stream) {
    const float* x  = (const float*)d_in[0];
    const int*   ei = (const int*)d_in[1];
    const float* W1 = (const float*)d_in[2];
    const float* b1 = (const float*)d_in[3];
    const float* W2 = (const float*)d_in[4];
    const float* b2 = (const float*)d_in[5];

    int n = in_sizes[0] / D;   // 50000
    int E = in_sizes[1] / 2;   // 800000
    const int* src = ei;
    const int* dst = ei + E;

    char* ws = (char*)d_ws;
    auto take = [&](size_t bytes) {
        char* p = ws;
        ws += (bytes + 255) & ~(size_t)255;
        return p;
    };
    int nb = (n + 255) / 256;  // 196
    // deg padded to multiple of 4 ints for the int4 zero kernel
    int*   deg     = (int*)take((size_t)((n + 3) & ~3) * sizeof(int));
    float* dinv    = (float*)take((size_t)n * sizeof(float));
    float* sd      = (float*)take((size_t)n * sizeof(float));
    int*   row_ptr = (int*)take((size_t)(n + 1) * sizeof(int));
    int*   bsum    = (int*)take((size_t)nb * sizeof(int));
    int*   rank    = (int*)take((size_t)E * sizeof(int));
    int*   csr_src = (int*)take((size_t)E * sizeof(int));
    float* agg     = (float*)take((size_t)n * D * sizeof(float));

    float* out = (float*)d_out;
    const int B = 256;

    int n4 = (n + 3) / 4;
    k_zero<<<(n4 + B - 1) / B, B, 0, stream>>>(deg, n4);
    k_deg_count<<<(E / 4 + B - 1) / B, B, 0, stream>>>(dst, E, deg, rank);

    k_scan_partial<<<nb, 256, 0, stream>>>(deg, n, bsum, dinv);
    k_scan_bsum<<<1, 256, 0, stream>>>(bsum, nb);
    k_scan_final<<<nb, 256, 0, stream>>>(deg, n, bsum, row_ptr);

    k_bucket<<<((E + 1) / 2 + B - 1) / B, B, 0, stream>>>(src, dst, rank, E,
                                                          row_ptr, csr_src);

    k_gather<<<(n + 3) / 4, 256, 0, stream>>>(x, dinv, row_ptr, csr_src, agg, n);

    k_gemm<<<(n + 4 * NPW - 1) / (4 * NPW), 256, 0, stream>>>(agg, dinv, W1, b1,
                                                              W2, sd, n);

    k_out<<<((size_t)n * 4 + B - 1) / B, B, 0, stream>>>(sd, dinv, row_ptr, csr_src,
                                                         b2, out, n);
}

// Round 8
// 121.244 us; speedup vs baseline: 1.0222x; 1.0222x over previous
//
#include <hip/hip_runtime.h>

#define D 64

// ---------- zero deg ----------
__global__ void k_zero(int* __restrict__ p, int n4) {
    int i = blockIdx.x * blockDim.x + threadIdx.x;
    if (i < n4) *(int4*)&p[i * 4] = make_int4(0, 0, 0, 0);
}

// ---------- in-degree count + per-edge rank: 4 edges/thread ----------
__global__ void k_deg_count(const int* __restrict__ dst, int E, int* deg,
                            int* __restrict__ rank) {
    int i = blockIdx.x * blockDim.x + threadIdx.x;
    int e = i * 4;
    if (e + 4 <= E) {
        int4 d4 = *(const int4*)&dst[e];
        int4 r4;
        r4.x = atomicAdd(&deg[d4.x], 1);
        r4.y = atomicAdd(&deg[d4.y], 1);
        r4.z = atomicAdd(&deg[d4.z], 1);
        r4.w = atomicAdd(&deg[d4.w], 1);
        *(int4*)&rank[e] = r4;   // coalesced
    } else if (e < E) {
        for (; e < E; ++e) rank[e] = atomicAdd(&deg[dst[e]], 1);
    }
}

// ---------- scan phase 1: per-block sums of deg; also dinv = rsqrt(deg+1) ----------
__global__ __launch_bounds__(256) void k_scan_partial(const int* __restrict__ deg,
                                                      int n, int* __restrict__ bsum,
                                                      float* __restrict__ dinv) {
    __shared__ int red[256];
    int t = threadIdx.x;
    int i = blockIdx.x * 256 + t;
    int d = (i < n) ? deg[i] : 0;
    if (i < n) dinv[i] = rsqrtf((float)(d + 1));  // +1 = self-loop
    red[t] = d;
    __syncthreads();
    for (int off = 128; off >= 1; off >>= 1) {
        if (t < off) red[t] += red[t + off];
        __syncthreads();
    }
    if (t == 0) bsum[blockIdx.x] = red[0];
}

// ---------- scan phase 2: row_ptr; each block redundantly scans bsum in LDS ----------
__global__ __launch_bounds__(256) void k_scan_final(const int* __restrict__ deg, int n,
                                                    const int* __restrict__ bsum, int nb,
                                                    int* row_ptr) {
    __shared__ int bs[256];
    __shared__ int sh[256];
    int t = threadIdx.x;
    // scan the (<=256) block sums — redundant per block, trivial cost
    bs[t] = (t < nb) ? bsum[t] : 0;
    __syncthreads();
    for (int off = 1; off < 256; off <<= 1) {
        int v = (t >= off) ? bs[t - off] : 0;
        __syncthreads();
        bs[t] += v;
        __syncthreads();
    }
    int block_off = (blockIdx.x == 0) ? 0 : bs[blockIdx.x - 1];

    int i = blockIdx.x * 256 + t;
    int val = (i < n) ? deg[i] : 0;
    sh[t] = val;
    __syncthreads();
    for (int off = 1; off < 256; off <<= 1) {
        int v = (t >= off) ? sh[t - off] : 0;
        __syncthreads();
        sh[t] += v;
        __syncthreads();
    }
    int excl = block_off + sh[t] - val;
    if (i < n) row_ptr[i] = excl;
    if (i == n - 1) row_ptr[n] = excl + val;  // = E
}

// ---------- bucket: NO atomics; pos = row_ptr[dst] + rank; 2 edges/thread ----------
__global__ void k_bucket(const int* __restrict__ src, const int* __restrict__ dst,
                         const int* __restrict__ rank, int E,
                         const int* __restrict__ row_ptr, int* __restrict__ csr_src) {
    int i = blockIdx.x * blockDim.x + threadIdx.x;
    int e = i * 2;
    if (e >= E) return;
    int2 s2 = *(const int2*)&src[e];
    int2 d2 = *(const int2*)&dst[e];
    int2 r2 = *(const int2*)&rank[e];
    csr_src[row_ptr[d2.x] + r2.x] = s2.x;
    if (e + 1 < E) csr_src[row_ptr[d2.y] + r2.y] = s2.y;
}

// ---------- gather: 1 node/wave, 4 edge-slots x 16 dim-groups, 4-deep pipeline ----------
__global__ __launch_bounds__(256) void k_gather(
        const float* __restrict__ x, const float* __restrict__ dinv,
        const int* __restrict__ row_ptr, const int* __restrict__ csr_src,
        float* __restrict__ agg, int n) {
    int tid = threadIdx.x;
    int wave = tid >> 6, lane = tid & 63;
    int eg = lane >> 4, dg = lane & 15;
    int v = blockIdx.x * 4 + wave;
    if (v >= n) return;
    float dv = dinv[v];
    int beg = row_ptr[v], end = row_ptr[v + 1];

    float4 acc = make_float4(0.f, 0.f, 0.f, 0.f);
    if (eg == 0) {  // self-loop term
        float4 xv = *(const float4*)&x[(size_t)v * D + dg * 4];
        float w = dv * dv;
        acc.x = xv.x * w; acc.y = xv.y * w; acc.z = xv.z * w; acc.w = xv.w * w;
    }
    int base = beg;
    // 16 edges in flight: 4 independent csr->dinv->x chains
    for (; base + 16 <= end; base += 16) {
        int u0 = csr_src[base + eg];
        int u1 = csr_src[base + 4 + eg];
        int u2 = csr_src[base + 8 + eg];
        int u3 = csr_src[base + 12 + eg];
        float n0 = dinv[u0] * dv, n1 = dinv[u1] * dv;
        float n2 = dinv[u2] * dv, n3 = dinv[u3] * dv;
        float4 x0 = *(const float4*)&x[(size_t)u0 * D + dg * 4];
        float4 x1 = *(const float4*)&x[(size_t)u1 * D + dg * 4];
        float4 x2 = *(const float4*)&x[(size_t)u2 * D + dg * 4];
        float4 x3 = *(const float4*)&x[(size_t)u3 * D + dg * 4];
        acc.x = fmaf(x0.x, n0, acc.x); acc.y = fmaf(x0.y, n0, acc.y);
        acc.z = fmaf(x0.z, n0, acc.z); acc.w = fmaf(x0.w, n0, acc.w);
        acc.x = fmaf(x1.x, n1, acc.x); acc.y = fmaf(x1.y, n1, acc.y);
        acc.z = fmaf(x1.z, n1, acc.z); acc.w = fmaf(x1.w, n1, acc.w);
        acc.x = fmaf(x2.x, n2, acc.x); acc.y = fmaf(x2.y, n2, acc.y);
        acc.z = fmaf(x2.z, n2, acc.z); acc.w = fmaf(x2.w, n2, acc.w);
        acc.x = fmaf(x3.x, n3, acc.x); acc.y = fmaf(x3.y, n3, acc.y);
        acc.z = fmaf(x3.z, n3, acc.z); acc.w = fmaf(x3.w, n3, acc.w);
    }
    for (; base + 8 <= end; base += 8) {
        int u0 = csr_src[base + eg];
        int u1 = csr_src[base + 4 + eg];
        float n0 = dinv[u0] * dv, n1 = dinv[u1] * dv;
        float4 x0 = *(const float4*)&x[(size_t)u0 * D + dg * 4];
        float4 x1 = *(const float4*)&x[(size_t)u1 * D + dg * 4];
        acc.x = fmaf(x0.x, n0, acc.x); acc.y = fmaf(x0.y, n0, acc.y);
        acc.z = fmaf(x0.z, n0, acc.z); acc.w = fmaf(x0.w, n0, acc.w);
        acc.x = fmaf(x1.x, n1, acc.x); acc.y = fmaf(x1.y, n1, acc.y);
        acc.z = fmaf(x1.z, n1, acc.z); acc.w = fmaf(x1.w, n1, acc.w);
    }
    for (; base < end; base += 4) {
        int idx = base + eg;
        if (idx < end) {
            int u = csr_src[idx];
            float nrm = dinv[u] * dv;
            float4 xv = *(const float4*)&x[(size_t)u * D + dg * 4];
            acc.x = fmaf(xv.x, nrm, acc.x); acc.y = fmaf(xv.y, nrm, acc.y);
            acc.z = fmaf(xv.z, nrm, acc.z); acc.w = fmaf(xv.w, nrm, acc.w);
        }
    }
#pragma unroll
    for (int off = 16; off <= 32; off <<= 1) {
        acc.x += __shfl_xor(acc.x, off, 64);
        acc.y += __shfl_xor(acc.y, off, 64);
        acc.z += __shfl_xor(acc.z, off, 64);
        acc.w += __shfl_xor(acc.w, off, 64);
    }
    if (eg == 0) *(float4*)&agg[(size_t)v * D + dg * 4] = acc;
}

// ---------- dense GEMM + relu + W2-dot: wave per node, 16 nodes/wave ----------
#define NPW 16
__global__ __launch_bounds__(256) void k_gemm(
        const float* __restrict__ agg, const float* __restrict__ dinv,
        const float* __restrict__ W1, const float* __restrict__ b1,
        const float* __restrict__ W2, float* __restrict__ sd, int n) {
    __shared__ float lrow[4][D];
    int tid = threadIdx.x;
    int wave = tid >> 6, lane = tid & 63;
    float w1c[D];
#pragma unroll
    for (int d = 0; d < D; ++d) w1c[d] = W1[d * D + lane];
    float b1l = b1[lane], w2l = W2[lane];
    int v0 = (blockIdx.x * 4 + wave) * NPW;
    for (int k = 0; k < NPW; ++k) {
        int v = v0 + k;
        if (v >= n) break;
        lrow[wave][lane] = agg[(size_t)v * D + lane];  // coalesced 256B
        __builtin_amdgcn_wave_barrier();
        float h = b1l;
#pragma unroll
        for (int db = 0; db < D; db += 4) {
            float4 r = *(const float4*)&lrow[wave][db];  // broadcast ds_read_b128
            h = fmaf(r.x, w1c[db], h);
            h = fmaf(r.y, w1c[db + 1], h);
            h = fmaf(r.z, w1c[db + 2], h);
            h = fmaf(r.w, w1c[db + 3], h);
        }
        float tt = fmaxf(h, 0.0f) * w2l;
#pragma unroll
        for (int off = 1; off <= 32; off <<= 1) tt += __shfl_xor(tt, off, 64);
        if (lane == 0) sd[v] = tt * dinv[v];  // s[v] * dinv[v]
        __builtin_amdgcn_wave_barrier();
    }
}

// ---------- layer-2: 8 lanes per node gather over CSR ----------
__global__ __launch_bounds__(256) void k_out(const float* __restrict__ sd,
        const float* __restrict__ dinv, const int* __restrict__ row_ptr,
        const int* __restrict__ csr_src, const float* __restrict__ b2,
        float* __restrict__ out, int n) {
    int t = blockIdx.x * blockDim.x + threadIdx.x;
    int v = t >> 3, r = t & 7;
    if (v >= n) return;
    int beg = row_ptr[v], end = row_ptr[v + 1];
    float a = (r == 0) ? sd[v] : 0.0f;  // self-loop
    for (int i = beg + r; i < end; i += 8) a += sd[csr_src[i]];
    a += __shfl_xor(a, 1, 64);
    a += __shfl_xor(a, 2, 64);
    a += __shfl_xor(a, 4, 64);
    if (r == 0) out[v] = b2[0] + a * dinv[v];
}

extern "C" void kernel_launch(void* const* d_in, const int* in_sizes, int n_in,
                              void* d_out, int out_size, void* d_ws, size_t ws_size,
                              hipStream_t stream) {
    const float* x  = (const float*)d_in[0];
    const int*   ei = (const int*)d_in[1];
    const float* W1 = (const float*)d_in[2];
    const float* b1 = (const float*)d_in[3];
    const float* W2 = (const float*)d_in[4];
    const float* b2 = (const float*)d_in[5];

    int n = in_sizes[0] / D;   // 50000
    int E = in_sizes[1] / 2;   // 800000
    const int* src = ei;
    const int* dst = ei + E;

    char* ws = (char*)d_ws;
    auto take = [&](size_t bytes) {
        char* p = ws;
        ws += (bytes + 255) & ~(size_t)255;
        return p;
    };
    int nb = (n + 255) / 256;  // 196
    int*   deg     = (int*)take((size_t)((n + 3) & ~3) * sizeof(int));
    float* dinv    = (float*)take((size_t)n * sizeof(float));
    float* sd      = (float*)take((size_t)n * sizeof(float));
    int*   row_ptr = (int*)take((size_t)(n + 1) * sizeof(int));
    int*   bsum    = (int*)take((size_t)nb * sizeof(int));
    int*   rank    = (int*)take((size_t)E * sizeof(int));
    int*   csr_src = (int*)take((size_t)E * sizeof(int));
    float* agg     = (float*)take((size_t)n * D * sizeof(float));

    float* out = (float*)d_out;
    const int B = 256;

    int n4 = (n + 3) / 4;
    k_zero<<<(n4 + B - 1) / B, B, 0, stream>>>(deg, n4);
    k_deg_count<<<(E / 4 + B - 1) / B, B, 0, stream>>>(dst, E, deg, rank);

    k_scan_partial<<<nb, 256, 0, stream>>>(deg, n, bsum, dinv);
    k_scan_final<<<nb, 256, 0, stream>>>(deg, n, bsum, nb, row_ptr);

    k_bucket<<<((E + 1) / 2 + B - 1) / B, B, 0, stream>>>(src, dst, rank, E,
                                                          row_ptr, csr_src);

    k_gather<<<(n + 3) / 4, 256, 0, stream>>>(x, dinv, row_ptr, csr_src, agg, n);

    k_gemm<<<(n + 4 * NPW - 1) / (4 * NPW), 256, 0, stream>>>(agg, dinv, W1, b1,
                                                              W2, sd, n);

    k_out<<<((size_t)n * 8 + B - 1) / B, B, 0, stream>>>(sd, dinv, row_ptr, csr_src,
                                                         b2, out, n);
}